// Round 9
// baseline (293.224 us; speedup 1.0000x reference)
//
#include <hip/hip_runtime.h>
#include <math.h>

#define SQRT3F     1.7320508075688772f
#define SCALE_T    0.17677669529663687f    // 1/sqrt(32)
#define SCALE_M1   0.025515518153991442f   // C_SCALAR/sqrt(32)
#define SCALE_M2   0.014731391274719739f   // C_SCALAR*inv_sqrt3/sqrt(32)
#define SCALE_M34  0.036084391824351615f   // C_SCALAR/4  (== C_VECTOR*inv_sqrt3/sqrt(16))

#define SSTR 36    // LDS stride (floats) for s rows
#define VSTR 52    // LDS stride (floats) for v rows

// quad broadcast of lane TT via DPP (VALU pipe, not DS)
template<int TT>
__device__ __forceinline__ float qb(float x) {
    return __int_as_float(__builtin_amdgcn_update_dpp(
        0, __float_as_int(x), TT * 0x55, 0xF, 0xF, true));
}

__device__ __forceinline__ int lower_bound_src(const int* __restrict__ src, int E, int key)
{
    int lo = 0, hi = E;
    while (lo < hi) {
        int mid = (lo + hi) >> 1;
        if (src[mid] < key) lo = mid + 1; else hi = mid;
    }
    return lo;
}

// ---------------------------------------------------------------------------
// Prep kernel, flat-indexed ranges:
//   [0, N)                degree-sort permutation (32-lane groups = 1 graph)
//   [.., +E)              jsh table float4(sh_xyz, bits(j&31))
//   [.., +N+1)            rowptr via binary search
//   [.., +weights)        folded weight matrices T/Ms/Mv
// ---------------------------------------------------------------------------
__global__ void prep_kernel(const float* __restrict__ pos,
                            const int* __restrict__ src, const int* __restrict__ col,
                            int E, int N,
                            const float* __restrict__ emb,
                            const float* __restrict__ W_s2n,
                            const float* __restrict__ W1, const float* __restrict__ W2,
                            const float* __restrict__ W3, const float* __restrict__ W4,
                            const float* __restrict__ Ws, const float* __restrict__ Wv,
                            float4* __restrict__ jsh, int* __restrict__ rowptr,
                            int* __restrict__ perm,
                            float* __restrict__ T, float* __restrict__ Ms,
                            float* __restrict__ Mv)
{
    int idx = blockIdx.x * blockDim.x + threadIdx.x;
    if (idx < N) {
        // one 32-lane group = one graph of 32 nodes; lane = local node
        int lane = idx & 63;
        int g32  = lane & 32;               // group base within wave (0 or 32)
        int n = idx;
        int d0 = lower_bound_src(src, E, n);
        int d1 = lower_bound_src(src, E, n + 1);
        int deg = d1 - d0;
        int rank = 0;
        #pragma unroll 8
        for (int kk = 0; kk < 32; ++kk) {
            int k = g32 + kk;
            int dk = __shfl(deg, k, 64);
            rank += (dk > deg) || (dk == deg && k < lane);
        }
        // descending degree within the graph: rank 0 = highest degree
        perm[(idx & ~31) + rank] = lane & 31;
        return;
    }
    idx -= N;
    if (idx < E) {
        int e = idx;
        int n = src[e], j = col[e];
        float dx = pos[3*n+0] - pos[3*j+0];
        float dy = pos[3*n+1] - pos[3*j+1];
        float dz = pos[3*n+2] - pos[3*j+2];
        float rinv = rsqrtf(dx*dx + dy*dy + dz*dz) * SQRT3F;
        jsh[e] = make_float4(dx*rinv, dy*rinv, dz*rinv, __int_as_float(j & 31));
        return;
    }
    idx -= E;
    if (idx <= N) {
        rowptr[idx] = lower_bound_src(src, E, idx);
        return;
    }
    idx -= (N + 1);
    if (idx < 3200) {
        int r = idx >> 5, c = idx & 31;
        float acc = 0.f;
        for (int k = 0; k < 32; ++k) acc += emb[r*32 + k] * W_s2n[k*32 + c];
        T[idx] = acc * SCALE_T;
    } else if (idx < 3200 + 3*1536) {
        int tix = idx - 3200;
        int l = tix / 1536, rem = tix % 1536;
        int u = rem >> 5, w = rem & 31;
        float acc = 0.f;
        if (u < 32) {
            for (int k = 0; k < 32; ++k)
                acc += W1[l*1024 + u*32 + k] * Ws[l*1024 + k*32 + w];
            acc *= SCALE_M1;
        } else {
            int uu = u - 32;
            for (int k = 0; k < 32; ++k)
                acc += W4[l*512 + uu*32 + k] * Ws[l*1024 + k*32 + w];
            acc *= SCALE_M2;
        }
        Ms[l*1536 + u*32 + w] = acc;
    } else if (idx < 3200 + 3*1536 + 3*768) {
        int tix = idx - 3200 - 3*1536;
        int l = tix / 768, rem = tix % 768;
        int u = rem >> 4, w = rem & 15;
        float acc = 0.f;
        if (u < 32) {
            for (int k = 0; k < 16; ++k)
                acc += W2[l*512 + u*16 + k] * Wv[l*256 + k*16 + w];
        } else {
            int uu = u - 32;
            for (int k = 0; k < 16; ++k)
                acc += W3[l*256 + uu*16 + k] * Wv[l*256 + k*16 + w];
        }
        Mv[l*768 + u*16 + w] = acc * SCALE_M34;
    }
}

// ---------------------------------------------------------------------------
// Phase-2 contribution from quad-lane TT (DPP broadcasts + folded-M FMAs).
// Runs per quad on that quad's (edge-half) partial aggregates — phase 2 is
// linear in the aggregates, so halves are combined on the OUTPUTS.
// ---------------------------------------------------------------------------
template<int TT>
__device__ __forceinline__ void p2(const float (&a0)[8], const float (&a1)[8][3],
                                   const float (&a2)[4][3], const float (&a3)[4],
                                   const float* __restrict__ Msg,
                                   const float* __restrict__ Mvg,
                                   int t, bool hasv,
                                   float (&po)[8], float (&pv)[12])
{
    #pragma unroll
    for (int k = 0; k < 8; ++k) {
        const int u = 8*TT + k;
        float a  = qb<TT>(a0[k]);
        float bx = qb<TT>(a1[k][0]);
        float by = qb<TT>(a1[k][1]);
        float bz = qb<TT>(a1[k][2]);
        const float4* r = (const float4*)(Msg + u*32 + 8*t);
        float4 rA = r[0], rB = r[1];
        po[0]=fmaf(a,rA.x,po[0]); po[1]=fmaf(a,rA.y,po[1]);
        po[2]=fmaf(a,rA.z,po[2]); po[3]=fmaf(a,rA.w,po[3]);
        po[4]=fmaf(a,rB.x,po[4]); po[5]=fmaf(a,rB.y,po[5]);
        po[6]=fmaf(a,rB.z,po[6]); po[7]=fmaf(a,rB.w,po[7]);
        float4 m = *(const float4*)(Mvg + u*16 + 4*t);
        pv[0]=fmaf(m.x,bx,pv[0]);  pv[1]=fmaf(m.x,by,pv[1]);  pv[2]=fmaf(m.x,bz,pv[2]);
        pv[3]=fmaf(m.y,bx,pv[3]);  pv[4]=fmaf(m.y,by,pv[4]);  pv[5]=fmaf(m.y,bz,pv[5]);
        pv[6]=fmaf(m.z,bx,pv[6]);  pv[7]=fmaf(m.z,by,pv[7]);  pv[8]=fmaf(m.z,bz,pv[8]);
        pv[9]=fmaf(m.w,bx,pv[9]);  pv[10]=fmaf(m.w,by,pv[10]); pv[11]=fmaf(m.w,bz,pv[11]);
    }
    if (hasv) {
        #pragma unroll
        for (int k = 0; k < 4; ++k) {
            const int u = 32 + 4*TT + k;
            float a  = qb<TT>(a3[k]);
            float bx = qb<TT>(a2[k][0]);
            float by = qb<TT>(a2[k][1]);
            float bz = qb<TT>(a2[k][2]);
            const float4* r = (const float4*)(Msg + u*32 + 8*t);
            float4 rA = r[0], rB = r[1];
            po[0]=fmaf(a,rA.x,po[0]); po[1]=fmaf(a,rA.y,po[1]);
            po[2]=fmaf(a,rA.z,po[2]); po[3]=fmaf(a,rA.w,po[3]);
            po[4]=fmaf(a,rB.x,po[4]); po[5]=fmaf(a,rB.y,po[5]);
            po[6]=fmaf(a,rB.z,po[6]); po[7]=fmaf(a,rB.w,po[7]);
            float4 m = *(const float4*)(Mvg + u*16 + 4*t);
            pv[0]=fmaf(m.x,bx,pv[0]);  pv[1]=fmaf(m.x,by,pv[1]);  pv[2]=fmaf(m.x,bz,pv[2]);
            pv[3]=fmaf(m.y,bx,pv[3]);  pv[4]=fmaf(m.y,by,pv[4]);  pv[5]=fmaf(m.y,bz,pv[5]);
            pv[6]=fmaf(m.z,bx,pv[6]);  pv[7]=fmaf(m.z,by,pv[7]);  pv[8]=fmaf(m.z,bz,pv[8]);
            pv[9]=fmaf(m.w,bx,pv[9]);  pv[10]=fmaf(m.w,by,pv[10]); pv[11]=fmaf(m.w,bz,pv[11]);
        }
    }
}

// ---------------------------------------------------------------------------
// Fused GNN: one block = 1 graph (32 nodes, 256 threads, 8 lanes/node).
// Lane = (t = channel quad 0..3, h = edge half 0/1): each lane owns the same
// channel slice as before but sums only every 2nd edge -> trip count halves,
// and the grid doubles to 2048 blocks = 8 blocks/CU = 32 waves/CU (the
// previous 4-lane layout was grid-capped at 16 waves/CU; latency-bound at
// VALUBusy 30%). Phase-2 runs per quad on edge-half partials (linear), and
// the 20 outputs are combined with 12 shfl_xor(4); h=0 writes s, h=1 writes v.
// NOTE: do not force min-waves higher — (256,6) at 4 lanes forced 40 VGPRs
// and spilled accumulators (round 5: 500 MB scratch traffic, 2.3x slower).
// ---------------------------------------------------------------------------
__global__ __launch_bounds__(256, 4)
void gnn_kernel(const float* __restrict__ T, const int* __restrict__ z,
                const int* __restrict__ rowptr, const int* __restrict__ perm,
                const float4* __restrict__ jsh,
                const float* __restrict__ Ms, const float* __restrict__ Mv,
                float* __restrict__ hg, int N)
{
    __shared__ __align__(16) float sS[32*SSTR];
    __shared__ __align__(16) float sV[32*VSTR];
    __shared__ int rp[33];

    const int base = blockIdx.x * 32;
    const int tid = threadIdx.x;

    if (tid < 33) rp[tid] = rowptr[base + tid];
    for (int i = tid; i < 32*VSTR; i += 256) sV[i] = 0.f;
    for (int i = tid; i < 1024; i += 256) {
        int n = i >> 5, c = i & 31;
        sS[n*SSTR + c] = T[z[base + n]*32 + c];
    }
    const int pl = perm[base + (tid >> 3)];   // my node (local 0..31), degree-sorted
    const int t  = tid & 3;                   // channel quad: s-ch 8t.., v-ch 4t..
    const int h  = (tid >> 2) & 1;            // edge half
    __syncthreads();

    const int el0 = rp[pl], el1 = rp[pl + 1];  // global edge range

    for (int lay = 0; lay < 3; ++lay) {
        const bool hasv = (lay != 0);
        const float* Msg = Ms + lay*1536;
        const float* Mvg = Mv + lay*768;

        float a0[8]    = {};
        float a1[8][3] = {};
        float a2[4][3] = {};
        float a3[4]    = {};

        if (!hasv) {
            for (int e = el0 + h; e < el1; e += 2) {
                float4 js = jsh[e];
                int jl = __float_as_int(js.w);
                const float* Sj = sS + jl*SSTR + 8*t;
                float4 sA = *(const float4*)Sj;
                float4 sB = *(const float4*)(Sj + 4);
                float ssv[8] = {sA.x,sA.y,sA.z,sA.w,sB.x,sB.y,sB.z,sB.w};
                #pragma unroll
                for (int k = 0; k < 8; ++k) {
                    a0[k] += ssv[k];
                    a1[k][0] = fmaf(ssv[k], js.x, a1[k][0]);
                    a1[k][1] = fmaf(ssv[k], js.y, a1[k][1]);
                    a1[k][2] = fmaf(ssv[k], js.z, a1[k][2]);
                }
            }
        } else {
            for (int e = el0 + h; e < el1; e += 2) {
                float4 js = jsh[e];
                int jl = __float_as_int(js.w);
                const float* Sj = sS + jl*SSTR + 8*t;
                const float* Vj = sV + jl*VSTR + 12*t;
                float4 sA = *(const float4*)Sj;
                float4 sB = *(const float4*)(Sj + 4);
                float4 vA = *(const float4*)Vj;
                float4 vB = *(const float4*)(Vj + 4);
                float4 vC = *(const float4*)(Vj + 8);
                float ssv[8] = {sA.x,sA.y,sA.z,sA.w,sB.x,sB.y,sB.z,sB.w};
                #pragma unroll
                for (int k = 0; k < 8; ++k) {
                    a0[k] += ssv[k];
                    a1[k][0] = fmaf(ssv[k], js.x, a1[k][0]);
                    a1[k][1] = fmaf(ssv[k], js.y, a1[k][1]);
                    a1[k][2] = fmaf(ssv[k], js.z, a1[k][2]);
                }
                float vv[4][3] = {{vA.x,vA.y,vA.z},{vA.w,vB.x,vB.y},
                                  {vB.z,vB.w,vC.x},{vC.y,vC.z,vC.w}};
                #pragma unroll
                for (int k = 0; k < 4; ++k) {
                    a2[k][0] += vv[k][0]; a2[k][1] += vv[k][1]; a2[k][2] += vv[k][2];
                    a3[k] = fmaf(vv[k][0], js.x,
                            fmaf(vv[k][1], js.y, fmaf(vv[k][2], js.z, a3[k])));
                }
            }
        }
        __syncthreads();   // all gathers done before in-place update

        float po[8]  = {};
        float pv[12] = {};
        p2<0>(a0, a1, a2, a3, Msg, Mvg, t, hasv, po, pv);
        p2<1>(a0, a1, a2, a3, Msg, Mvg, t, hasv, po, pv);
        p2<2>(a0, a1, a2, a3, Msg, Mvg, t, hasv, po, pv);
        p2<3>(a0, a1, a2, a3, Msg, Mvg, t, hasv, po, pv);

        // combine edge-half partials on the outputs: h=0 needs full po,
        // h=1 needs full pv. Send what the partner needs (12 shfls).
        float comb[12];
        #pragma unroll
        for (int i = 0; i < 12; ++i) {
            float x;
            if (i < 8) x = h ? po[i] : pv[i];
            else       x = h ? 0.f   : pv[i];
            comb[i] = __shfl_xor(x, 4, 64);
        }

        if (h == 0) {
            // residual + relu, scalar slice of node pl
            float* Sp = sS + pl*SSTR + 8*t;
            float4 s0 = *(float4*)Sp, s1 = *(float4*)(Sp + 4);
            s0.x += fmaxf(po[0]+comb[0],0.f); s0.y += fmaxf(po[1]+comb[1],0.f);
            s0.z += fmaxf(po[2]+comb[2],0.f); s0.w += fmaxf(po[3]+comb[3],0.f);
            s1.x += fmaxf(po[4]+comb[4],0.f); s1.y += fmaxf(po[5]+comb[5],0.f);
            s1.z += fmaxf(po[6]+comb[6],0.f); s1.w += fmaxf(po[7]+comb[7],0.f);
            *(float4*)Sp = s0; *(float4*)(Sp + 4) = s1;
        } else {
            // residual + relu, vector slice of node pl
            float* Vp = sV + pl*VSTR + 12*t;
            float4 v0 = *(float4*)Vp, v1 = *(float4*)(Vp + 4), v2 = *(float4*)(Vp + 8);
            v0.x += fmaxf(pv[0]+comb[0],0.f);   v0.y += fmaxf(pv[1]+comb[1],0.f);
            v0.z += fmaxf(pv[2]+comb[2],0.f);   v0.w += fmaxf(pv[3]+comb[3],0.f);
            v1.x += fmaxf(pv[4]+comb[4],0.f);   v1.y += fmaxf(pv[5]+comb[5],0.f);
            v1.z += fmaxf(pv[6]+comb[6],0.f);   v1.w += fmaxf(pv[7]+comb[7],0.f);
            v2.x += fmaxf(pv[8]+comb[8],0.f);   v2.y += fmaxf(pv[9]+comb[9],0.f);
            v2.z += fmaxf(pv[10]+comb[10],0.f); v2.w += fmaxf(pv[11]+comb[11],0.f);
            *(float4*)Vp = v0; *(float4*)(Vp + 4) = v1; *(float4*)(Vp + 8) = v2;
        }

        __syncthreads();
    }

    // fused sum-pool: 1 graph x 80 features
    if (tid < 80) {
        int f = tid;
        float acc = 0.f;
        if (f < 32) {
            for (int k = 0; k < 32; ++k) acc += sS[k*SSTR + f];
        } else {
            int c = f - 32;
            for (int k = 0; k < 32; ++k) acc += sV[k*VSTR + c];
        }
        hg[(size_t)blockIdx.x*80 + f] = acc;
    }
}

// ---------------------------------------------------------------------------
// MLP head: 4 graphs per block; Wr1/Wr2 shared; split-K stage 2.
// ---------------------------------------------------------------------------
__launch_bounds__(256)
__global__ void mlp_kernel(const float* __restrict__ hg,
                           const float* __restrict__ Wr1, const float* __restrict__ br1,
                           const float* __restrict__ Wr2, const float* __restrict__ br2,
                           float* __restrict__ out, int B)
{
    __shared__ __align__(16) float h1[4][256];
    __shared__ float red[4][128];
    const int g0 = blockIdx.x * 4;
    const int w = threadIdx.x;

    float acc0 = br1[w];
    float acc1 = acc0, acc2 = acc0, acc3 = acc0;
    #pragma unroll 4
    for (int f = 0; f < 80; ++f) {
        float wv = Wr1[f*256 + w];
        acc0 = fmaf(hg[(size_t)(g0+0)*80 + f], wv, acc0);
        acc1 = fmaf(hg[(size_t)(g0+1)*80 + f], wv, acc1);
        acc2 = fmaf(hg[(size_t)(g0+2)*80 + f], wv, acc2);
        acc3 = fmaf(hg[(size_t)(g0+3)*80 + f], wv, acc3);
    }
    h1[0][w] = fmaxf(acc0, 0.f);
    h1[1][w] = fmaxf(acc1, 0.f);
    h1[2][w] = fmaxf(acc2, 0.f);
    h1[3][w] = fmaxf(acc3, 0.f);
    __syncthreads();

    const int w2 = threadIdx.x & 127, kh = threadIdx.x >> 7;
    const float4* h1v = (const float4*)(&h1[0][0]);   // [4][64] float4 view
    float s0 = 0.f, s1 = 0.f, s2 = 0.f, s3 = 0.f;
    #pragma unroll 2
    for (int k4 = kh*32; k4 < kh*32 + 32; ++k4) {
        float4 hA = h1v[0*64 + k4];
        float4 hB = h1v[1*64 + k4];
        float4 hC = h1v[2*64 + k4];
        float4 hD = h1v[3*64 + k4];
        int k = k4 * 4;
        float m0 = Wr2[(size_t)(k+0)*128 + w2];
        float m1 = Wr2[(size_t)(k+1)*128 + w2];
        float m2 = Wr2[(size_t)(k+2)*128 + w2];
        float m3 = Wr2[(size_t)(k+3)*128 + w2];
        s0 = fmaf(hA.x,m0, fmaf(hA.y,m1, fmaf(hA.z,m2, fmaf(hA.w,m3, s0))));
        s1 = fmaf(hB.x,m0, fmaf(hB.y,m1, fmaf(hB.z,m2, fmaf(hB.w,m3, s1))));
        s2 = fmaf(hC.x,m0, fmaf(hC.y,m1, fmaf(hC.z,m2, fmaf(hC.w,m3, s2))));
        s3 = fmaf(hD.x,m0, fmaf(hD.y,m1, fmaf(hD.z,m2, fmaf(hD.w,m3, s3))));
    }
    if (kh) {
        red[0][w2] = s0; red[1][w2] = s1; red[2][w2] = s2; red[3][w2] = s3;
    }
    __syncthreads();
    if (!kh) {
        float b = br2[w2];
        out[(size_t)(g0+0)*128 + w2] = s0 + red[0][w2] + b;
        out[(size_t)(g0+1)*128 + w2] = s1 + red[1][w2] + b;
        out[(size_t)(g0+2)*128 + w2] = s2 + red[2][w2] + b;
        out[(size_t)(g0+3)*128 + w2] = s3 + red[3][w2] + b;
    }
}

// ---------------------------------------------------------------------------
extern "C" void kernel_launch(void* const* d_in, const int* in_sizes, int n_in,
                              void* d_out, int out_size, void* d_ws, size_t ws_size,
                              hipStream_t stream)
{
    const float* pos   = (const float*)d_in[0];
    const int*   z     = (const int*)d_in[1];
    const int*   eidx  = (const int*)d_in[3];
    const float* emb   = (const float*)d_in[5];
    const float* W_s2n = (const float*)d_in[6];
    const float* W1    = (const float*)d_in[7];
    const float* W2    = (const float*)d_in[8];
    const float* W3    = (const float*)d_in[9];
    const float* W4    = (const float*)d_in[10];
    const float* Ws    = (const float*)d_in[11];
    const float* Wv    = (const float*)d_in[12];
    const float* Wr1   = (const float*)d_in[13];
    const float* br1   = (const float*)d_in[14];
    const float* Wr2   = (const float*)d_in[15];
    const float* br2   = (const float*)d_in[16];
    float* out = (float*)d_out;

    const int N = in_sizes[0] / 3;
    const int E = in_sizes[3] / 2;
    const int B = out_size / 128;

    const int* src = eidx;
    const int* col = eidx + E;

    // workspace layout (16B-aligned chunks)
    char* p = (char*)d_ws;
    float4* jsh = (float4*)p;  p += (size_t)E * 16;
    float* T  = (float*)p;     p += 3200 * 4;
    float* Ms = (float*)p;     p += 3 * 1536 * 4;
    float* Mv = (float*)p;     p += 3 * 768 * 4;
    int* rowptr = (int*)p;     p += (((size_t)(N + 1) * 4 + 15) & ~(size_t)15);
    int* perm = (int*)p;       p += (size_t)N * 4;
    float* hg = (float*)p;     p += (size_t)B * 80 * 4;

    const int prep_total = N + E + (N + 1) + 3200 + 3*1536 + 3*768;
    prep_kernel<<<(prep_total + 255) / 256, 256, 0, stream>>>(
        pos, src, col, E, N, emb, W_s2n, W1, W2, W3, W4, Ws, Wv,
        jsh, rowptr, perm, T, Ms, Mv);

    gnn_kernel<<<N / 32, 256, 0, stream>>>(T, z, rowptr, perm, jsh, Ms, Mv, hg, N);

    mlp_kernel<<<B / 4, 256, 0, stream>>>(hg, Wr1, br1, Wr2, br2, out, B);
}

// Round 10
// 125.876 us; speedup vs baseline: 2.3295x; 2.3295x over previous
//
#include <hip/hip_runtime.h>
#include <math.h>

typedef __attribute__((ext_vector_type(8))) short bf16x8;   // 8 bf16 (4 VGPRs)
typedef __attribute__((ext_vector_type(4))) float f32x4;    // MFMA acc

#define SQRT3F     1.7320508075688772f
#define SCALE_T    0.17677669529663687f    // 1/sqrt(32)
#define SCALE_M1   0.025515518153991442f   // C_SCALAR/sqrt(32)
#define SCALE_M2   0.014731391274719739f   // C_SCALAR*inv_sqrt3/sqrt(32)
#define SCALE_M34  0.036084391824351615f   // C_SCALAR/4

#define FSTR 40    // feature row stride (shorts): 80 B, 16B-aligned rows
#define ASTR 72    // agg / M row stride (shorts): 144 B, 16B-aligned rows

__device__ __forceinline__ ushort f2bf(float f) {
    union { float f; unsigned u; } v; v.f = f;
    unsigned u = v.u;
    return (ushort)((u + 0x7FFFu + ((u >> 16) & 1u)) >> 16);
}
__device__ __forceinline__ float bf2f(ushort h) {
    union { unsigned u; float f; } v; v.u = ((unsigned)h) << 16;
    return v.f;
}
__device__ __forceinline__ f32x4 mfma(bf16x8 a, bf16x8 b, f32x4 c) {
    return __builtin_amdgcn_mfma_f32_16x16x32_bf16(a, b, c, 0, 0, 0);
}
// D-tile -> agg[n][u0..u0+3] (4 consecutive u = 8 B), bf16
__device__ __forceinline__ void storeAgg(ushort* AG, f32x4 t, int u0, int n) {
    uint2 u;
    u.x = f2bf(t[0]) | ((unsigned)f2bf(t[1]) << 16);
    u.y = f2bf(t[2]) | ((unsigned)f2bf(t[3]) << 16);
    *(uint2*)&AG[n*ASTR + u0] = u;
}

// ---------------------------------------------------------------------------
// Prep: (A) adjacency MFMA fragments from positions (radius predicate, exact
// fp32 ops to match numpy), (B) Tbf = bf16(emb@W_s2n * sT), (C) Mbf = folded
// update matrices, transposed+bf16: rows 0..31 = MsT[w][u64], 32..47 = MvT.
// ---------------------------------------------------------------------------
__global__ void prep_kernel(const float* __restrict__ pos,
                            const float* __restrict__ emb,
                            const float* __restrict__ W_s2n,
                            const float* __restrict__ W1, const float* __restrict__ W2,
                            const float* __restrict__ W3, const float* __restrict__ W4,
                            const float* __restrict__ Ws, const float* __restrict__ Wv,
                            ushort* __restrict__ adjF, ushort* __restrict__ Tbf,
                            ushort* __restrict__ Mbf, int NG)
{
    int idx = blockIdx.x * blockDim.x + threadIdx.x;
    const int NA = NG * 2 * 64;
    if (idx < NA) {
        int g = idx >> 7, r = idx & 127, nt = r >> 6, l = r & 63;
        int nl = nt*16 + (l & 15);
        int k0 = (l >> 4) * 8;
        int ng = g*32 + nl;
        float px = pos[3*ng], py = pos[3*ng+1], pz = pos[3*ng+2];
        ushort o0[8], o1[8], o2[8], o3[8];
        #pragma unroll
        for (int jj = 0; jj < 8; ++jj) {
            int j = g*32 + k0 + jj;
            float dx = __fsub_rn(px, pos[3*j]);
            float dy = __fsub_rn(py, pos[3*j+1]);
            float dz = __fsub_rn(pz, pos[3*j+2]);
            float d2 = __fadd_rn(__fadd_rn(__fmul_rn(dx,dx), __fmul_rn(dy,dy)),
                                 __fmul_rn(dz,dz));
            bool on = (d2 <= 25.0f) && (d2 > 0.0f);
            float rinv = on ? rsqrtf(d2) * SQRT3F : 0.f;
            o0[jj] = on ? f2bf(1.0f) : 0;
            o1[jj] = f2bf(dx * rinv);
            o2[jj] = f2bf(dy * rinv);
            o3[jj] = f2bf(dz * rinv);
        }
        const ushort* srcs[4] = {o0, o1, o2, o3};
        #pragma unroll
        for (int w = 0; w < 4; ++w) {
            const ushort* s = srcs[w];
            uint4 u;
            u.x = s[0] | ((unsigned)s[1] << 16);
            u.y = s[2] | ((unsigned)s[3] << 16);
            u.z = s[4] | ((unsigned)s[5] << 16);
            u.w = s[6] | ((unsigned)s[7] << 16);
            *(uint4*)(adjF + (((size_t)(g*4 + w)*2 + nt)*64 + l)*8) = u;
        }
        return;
    }
    idx -= NA;
    if (idx < 3200) {
        int r = idx >> 5, c = idx & 31;
        float acc = 0.f;
        for (int k = 0; k < 32; ++k) acc += emb[r*32 + k] * W_s2n[k*32 + c];
        Tbf[idx] = f2bf(acc * SCALE_T);
        return;
    }
    idx -= 3200;
    if (idx < 3*48*64) {
        int lyr = idx / 3072, rem = idx % 3072;
        int row = rem >> 6, u = rem & 63;
        float val = 0.f;
        if (row < 32) {
            int w = row;
            if (u < 32) {
                float a = 0.f;
                for (int k = 0; k < 32; ++k)
                    a += W1[lyr*1024 + u*32 + k] * Ws[lyr*1024 + k*32 + w];
                val = a * SCALE_M1;
            } else if (u < 48) {
                int uu = u - 32; float a = 0.f;
                for (int k = 0; k < 32; ++k)
                    a += W4[lyr*512 + uu*32 + k] * Ws[lyr*1024 + k*32 + w];
                val = a * SCALE_M2;
            }
        } else {
            int w = row - 32;
            if (u < 32) {
                float a = 0.f;
                for (int k = 0; k < 16; ++k)
                    a += W2[lyr*512 + u*16 + k] * Wv[lyr*256 + k*16 + w];
                val = a * SCALE_M34;
            } else if (u < 48) {
                int uu = u - 32; float a = 0.f;
                for (int k = 0; k < 16; ++k)
                    a += W3[lyr*256 + uu*16 + k] * Wv[lyr*256 + k*16 + w];
                val = a * SCALE_M34;
            }
        }
        Mbf[lyr*3072 + row*64 + u] = f2bf(val);
    }
}

// ---------------------------------------------------------------------------
// Dense MFMA GNN: one wave = one graph (32 nodes); 4 graphs/block; 512 blocks
// = 2 blocks/CU, all co-resident. Per layer, per graph (all 16x16x32 bf16):
//   stage1 (transposed): aggT = featT x AdjF^T  -> written as B^T layout
//   stage2: h = M x agg  (M fragments from LDS, agg fragments from stage-1)
// Adjacency fragments live in 32 VGPRs for all 3 layers. No __syncthreads in
// the layer loop (wave-private LDS regions; in-wave LDS ordering via lgkmcnt).
// Fragment scheme = verified m89 "B^T" GEMM: A row m=l&15, B row n=l&15, both
// k = (l>>4)*8 contiguous; D: col=l&15, row=(l>>4)*4+reg.
// ---------------------------------------------------------------------------
__global__ __launch_bounds__(256)
void gnn_kernel(const ushort* __restrict__ Tbf, const int* __restrict__ z,
                const ushort* __restrict__ adjF, const ushort* __restrict__ Mbf,
                float* __restrict__ hg, int B)
{
    __shared__ ushort lM[3*48*ASTR];            // 20.7 KB: MsT/MvT, 3 layers
    __shared__ ushort feat[4][80*FSTR];         // 25.6 KB: per-graph sbfT(32)+vbfT(48)
    __shared__ ushort agg[4][32*ASTR];          // 18.4 KB: per-graph agg plane [n][u64]

    const int tid = threadIdx.x;
    // stage M (block-cooperative)
    for (int i = tid; i < 3*48*8; i += 256) {
        int row = i >> 3, u0 = (i & 7) * 8;
        uint4 m = *(const uint4*)(Mbf + row*64 + u0);
        uint2 a; a.x = m.x; a.y = m.y;
        uint2 b; b.x = m.z; b.y = m.w;
        *(uint2*)&lM[row*ASTR + u0]     = a;
        *(uint2*)&lM[row*ASTR + u0 + 4] = b;
    }
    const int wv = tid >> 6, l = tid & 63;
    const int g  = blockIdx.x*4 + wv;
    ushort* F  = feat[wv];
    ushort* AG = agg[wv];

    // zero agg (incl. K-pad cols 48..63, which stay 0 forever) and v rows
    for (int i = l; i < 32*(ASTR/2); i += 64) ((uint*)AG)[i] = 0;
    for (int i = l; i < 48*(FSTR/2); i += 64) ((uint*)(F + 32*FSTR))[i] = 0;
    // init sbfT[c][n] = Tbf[z[n]][c] (transposed)
    {
        int n = l & 31, h = l >> 5;
        int zg = z[g*32 + n];
        uint4 t0 = *(const uint4*)(Tbf + zg*32 + h*16);
        uint4 t1 = *(const uint4*)(Tbf + zg*32 + h*16 + 8);
        unsigned ua[8] = {t0.x, t0.y, t0.z, t0.w, t1.x, t1.y, t1.z, t1.w};
        #pragma unroll
        for (int q = 0; q < 8; ++q) {
            F[(h*16 + 2*q    )*FSTR + n] = (ushort)ua[q];
            F[(h*16 + 2*q + 1)*FSTR + n] = (ushort)(ua[q] >> 16);
        }
    }
    // adjacency fragments -> registers (layer-invariant)
    bf16x8 adjf[4][2];
    #pragma unroll
    for (int w = 0; w < 4; ++w)
        #pragma unroll
        for (int nt = 0; nt < 2; ++nt)
            adjf[w][nt] = *(const bf16x8*)(adjF + (((size_t)(g*4 + w)*2 + nt)*64 + l)*8);
    __syncthreads();

    const int ln = l & 15, kq = l >> 4;
    const f32x4 z4 = {0.f, 0.f, 0.f, 0.f};

    for (int lay = 0; lay < 3; ++lay) {
        const ushort* Msl = lM + lay*48*ASTR;
        // feature fragments (pre-update values, used by all paths this layer)
        bf16x8 fs0 = *(const bf16x8*)&F[(     ln)*FSTR + kq*8];
        bf16x8 fs1 = *(const bf16x8*)&F[(16 + ln)*FSTR + kq*8];
        bf16x8 fv0 = *(const bf16x8*)&F[(32 + ln)*FSTR + kq*8];
        bf16x8 fv1 = *(const bf16x8*)&F[(48 + ln)*FSTR + kq*8];
        bf16x8 fv2 = *(const bf16x8*)&F[(64 + ln)*FSTR + kq*8];

        // ---- scalar path: agg = [A0 (u<32) | a3 (u 32..47)]
        #pragma unroll
        for (int nt = 0; nt < 2; ++nt) {
            f32x4 t;
            t = mfma(fs0, adjf[0][nt], z4);            // A0, c-tile 0
            storeAgg(AG, t,      kq*4, nt*16 + ln);
            t = mfma(fs1, adjf[0][nt], z4);            // A0, c-tile 1
            storeAgg(AG, t, 16 + kq*4, nt*16 + ln);
            t = mfma(fv2, adjf[3][nt], z4);            // a3 = sum_i v_i x Adj_i
            t = mfma(fv1, adjf[2][nt], t);
            t = mfma(fv0, adjf[1][nt], t);
            storeAgg(AG, t, 32 + kq*4, nt*16 + ln);
        }
        // h_s = MsT x agg^T
        f32x4 hs[2][2] = {{z4, z4}, {z4, z4}};
        #pragma unroll
        for (int kc = 0; kc < 2; ++kc) {
            bf16x8 m0 = *(const bf16x8*)&Msl[(     ln)*ASTR + kc*32 + kq*8];
            bf16x8 m1 = *(const bf16x8*)&Msl[(16 + ln)*ASTR + kc*32 + kq*8];
            #pragma unroll
            for (int nt = 0; nt < 2; ++nt) {
                bf16x8 bg = *(const bf16x8*)&AG[(nt*16 + ln)*ASTR + kc*32 + kq*8];
                hs[0][nt] = mfma(m0, bg, hs[0][nt]);
                hs[1][nt] = mfma(m1, bg, hs[1][nt]);
            }
        }
        // s residual + relu (in place, bf16 master)
        #pragma unroll
        for (int mt = 0; mt < 2; ++mt)
            #pragma unroll
            for (int nt = 0; nt < 2; ++nt) {
                int n = nt*16 + ln;
                #pragma unroll
                for (int r = 0; r < 4; ++r) {
                    int c = mt*16 + kq*4 + r;
                    ushort* p = &F[c*FSTR + n];
                    *p = f2bf(bf2f(*p) + fmaxf(hs[mt][nt][r], 0.f));
                }
            }

        // ---- vector path, one spatial component i at a time (reuses AG)
        #pragma unroll
        for (int i = 0; i < 3; ++i) {
            bf16x8 fvi = (i == 0) ? fv0 : (i == 1) ? fv1 : fv2;
            #pragma unroll
            for (int nt = 0; nt < 2; ++nt) {
                f32x4 t;
                t = mfma(fs0, adjf[1+i][nt], z4);       // A1_i, c-tile 0
                storeAgg(AG, t,      kq*4, nt*16 + ln);
                t = mfma(fs1, adjf[1+i][nt], z4);       // A1_i, c-tile 1
                storeAgg(AG, t, 16 + kq*4, nt*16 + ln);
                t = mfma(fvi, adjf[0][nt], z4);         // a2_i
                storeAgg(AG, t, 32 + kq*4, nt*16 + ln);
            }
            f32x4 hv[2] = {z4, z4};
            #pragma unroll
            for (int kc = 0; kc < 2; ++kc) {
                bf16x8 mv = *(const bf16x8*)&Msl[(32 + ln)*ASTR + kc*32 + kq*8];
                #pragma unroll
                for (int nt = 0; nt < 2; ++nt) {
                    bf16x8 bg = *(const bf16x8*)&AG[(nt*16 + ln)*ASTR + kc*32 + kq*8];
                    hv[nt] = mfma(mv, bg, hv[nt]);
                }
            }
            #pragma unroll
            for (int nt = 0; nt < 2; ++nt) {
                int n = nt*16 + ln;
                #pragma unroll
                for (int r = 0; r < 4; ++r) {
                    int c = 32 + i*16 + kq*4 + r;
                    ushort* p = &F[c*FSTR + n];
                    *p = f2bf(bf2f(*p) + fmaxf(hv[nt][r], 0.f));
                }
            }
        }
    }

    // wave-local sum-pool: 80 features over 32 nodes
    for (int f = l; f < 80; f += 64) {
        const ushort* row;
        if (f < 32) row = &F[f*FSTR];
        else { int c = f - 32, w = c/3, i = c - 3*w; row = &F[(32 + i*16 + w)*FSTR]; }
        const uint* r32 = (const uint*)row;
        float acc = 0.f;
        #pragma unroll
        for (int q = 0; q < 16; ++q) {
            uint u = r32[q];
            acc += bf2f((ushort)u) + bf2f((ushort)(u >> 16));
        }
        hg[(size_t)g*80 + f] = acc;
    }
}

// ---------------------------------------------------------------------------
// MLP head: 4 graphs per block; Wr1/Wr2 shared; split-K stage 2. (fp32)
// ---------------------------------------------------------------------------
__launch_bounds__(256)
__global__ void mlp_kernel(const float* __restrict__ hg,
                           const float* __restrict__ Wr1, const float* __restrict__ br1,
                           const float* __restrict__ Wr2, const float* __restrict__ br2,
                           float* __restrict__ out, int B)
{
    __shared__ __align__(16) float h1[4][256];
    __shared__ float red[4][128];
    const int g0 = blockIdx.x * 4;
    const int w = threadIdx.x;

    float acc0 = br1[w];
    float acc1 = acc0, acc2 = acc0, acc3 = acc0;
    #pragma unroll 4
    for (int f = 0; f < 80; ++f) {
        float wv = Wr1[f*256 + w];
        acc0 = fmaf(hg[(size_t)(g0+0)*80 + f], wv, acc0);
        acc1 = fmaf(hg[(size_t)(g0+1)*80 + f], wv, acc1);
        acc2 = fmaf(hg[(size_t)(g0+2)*80 + f], wv, acc2);
        acc3 = fmaf(hg[(size_t)(g0+3)*80 + f], wv, acc3);
    }
    h1[0][w] = fmaxf(acc0, 0.f);
    h1[1][w] = fmaxf(acc1, 0.f);
    h1[2][w] = fmaxf(acc2, 0.f);
    h1[3][w] = fmaxf(acc3, 0.f);
    __syncthreads();

    const int w2 = threadIdx.x & 127, kh = threadIdx.x >> 7;
    const float4* h1v = (const float4*)(&h1[0][0]);
    float s0 = 0.f, s1 = 0.f, s2 = 0.f, s3 = 0.f;
    #pragma unroll 2
    for (int k4 = kh*32; k4 < kh*32 + 32; ++k4) {
        float4 hA = h1v[0*64 + k4];
        float4 hB = h1v[1*64 + k4];
        float4 hC = h1v[2*64 + k4];
        float4 hD = h1v[3*64 + k4];
        int k = k4 * 4;
        float m0 = Wr2[(size_t)(k+0)*128 + w2];
        float m1 = Wr2[(size_t)(k+1)*128 + w2];
        float m2 = Wr2[(size_t)(k+2)*128 + w2];
        float m3 = Wr2[(size_t)(k+3)*128 + w2];
        s0 = fmaf(hA.x,m0, fmaf(hA.y,m1, fmaf(hA.z,m2, fmaf(hA.w,m3, s0))));
        s1 = fmaf(hB.x,m0, fmaf(hB.y,m1, fmaf(hB.z,m2, fmaf(hB.w,m3, s1))));
        s2 = fmaf(hC.x,m0, fmaf(hC.y,m1, fmaf(hC.z,m2, fmaf(hC.w,m3, s2))));
        s3 = fmaf(hD.x,m0, fmaf(hD.y,m1, fmaf(hD.z,m2, fmaf(hD.w,m3, s3))));
    }
    if (kh) {
        red[0][w2] = s0; red[1][w2] = s1; red[2][w2] = s2; red[3][w2] = s3;
    }
    __syncthreads();
    if (!kh) {
        float b = br2[w2];
        out[(size_t)(g0+0)*128 + w2] = s0 + red[0][w2] + b;
        out[(size_t)(g0+1)*128 + w2] = s1 + red[1][w2] + b;
        out[(size_t)(g0+2)*128 + w2] = s2 + red[2][w2] + b;
        out[(size_t)(g0+3)*128 + w2] = s3 + red[3][w2] + b;
    }
}

// ---------------------------------------------------------------------------
extern "C" void kernel_launch(void* const* d_in, const int* in_sizes, int n_in,
                              void* d_out, int out_size, void* d_ws, size_t ws_size,
                              hipStream_t stream)
{
    const float* pos   = (const float*)d_in[0];
    const int*   z     = (const int*)d_in[1];
    const float* emb   = (const float*)d_in[5];
    const float* W_s2n = (const float*)d_in[6];
    const float* W1    = (const float*)d_in[7];
    const float* W2    = (const float*)d_in[8];
    const float* W3    = (const float*)d_in[9];
    const float* W4    = (const float*)d_in[10];
    const float* Ws    = (const float*)d_in[11];
    const float* Wv    = (const float*)d_in[12];
    const float* Wr1   = (const float*)d_in[13];
    const float* br1   = (const float*)d_in[14];
    const float* Wr2   = (const float*)d_in[15];
    const float* br2   = (const float*)d_in[16];
    float* out = (float*)d_out;

    const int B = out_size / 128;      // graphs (2048)
    const int NG = B;

    // workspace layout (16B-aligned chunks)
    char* p = (char*)d_ws;
    ushort* adjF = (ushort*)p;  p += (size_t)NG * 4 * 2 * 64 * 8 * 2;   // 16.78 MB
    ushort* Tbf  = (ushort*)p;  p += ((3200*2 + 15) & ~15);
    ushort* Mbf  = (ushort*)p;  p += ((3*48*64*2 + 15) & ~15);
    float*  hg   = (float*)p;   p += (size_t)B * 80 * 4;

    const int prep_total = NG*2*64 + 3200 + 3*48*64;
    prep_kernel<<<(prep_total + 255) / 256, 256, 0, stream>>>(
        pos, emb, W_s2n, W1, W2, W3, W4, Ws, Wv, adjF, Tbf, Mbf, NG);

    gnn_kernel<<<B / 4, 256, 0, stream>>>(Tbf, z, adjF, Mbf, hg, B);

    mlp_kernel<<<B / 4, 256, 0, stream>>>(hg, Wr1, br1, Wr2, br2, out, B);
}